// Round 18
// baseline (464.321 us; speedup 1.0000x reference)
//
#include <hip/hip_runtime.h>
#include <math.h>

#define B_ 8
#define C_ 256
#define S_ 9216
#define A_ 4
#define K_ 144
#define NB_ 64
#define SORTN 16384

typedef __bf16 bf16x8 __attribute__((ext_vector_type(8)));
typedef float f32x4 __attribute__((ext_vector_type(4)));
#define MFMA(a, b, c) __builtin_amdgcn_mfma_f32_16x16x32_bf16(a, b, c, 0, 0, 0)

// bf16 round-to-nearest-even
__device__ __forceinline__ unsigned short f2bf(float f) {
  unsigned int u = __float_as_uint(f);
  u = (u + 0x7FFFu + ((u >> 16) & 1u)) >> 16;
  return (unsigned short)u;
}
__device__ __forceinline__ float bf2f(unsigned short u) {
  return __uint_as_float(((unsigned int)u) << 16);
}

// ---------- transpose+convert: xf16[b][s][c] = bf16(in[b][c][s]) ----------
__global__ __launch_bounds__(256) void t_kernel(const float* __restrict__ in,
                                                unsigned short* __restrict__ xf16) {
  __shared__ float tile[32][33];
  int b = blockIdx.z;
  int c0 = blockIdx.y << 5, s0 = blockIdx.x << 5;
  int x = threadIdx.x & 31, y = threadIdx.x >> 5;  // 32 x 8
  const float* ip = in + ((size_t)b * C_ + c0 + y) * S_ + s0 + x;
#pragma unroll
  for (int k = 0; k < 32; k += 8) tile[y + k][x] = ip[(size_t)k * S_];
  __syncthreads();
  int xx = threadIdx.x & 15;        // c-pair 0..15 (32 c per tile)
  int yy = threadIdx.x >> 4;        // s row 0..15; two passes
#pragma unroll
  for (int k = 0; k < 32; k += 16) {
    int s = s0 + yy + k;
    unsigned int* dst = (unsigned int*)(xf16 + ((size_t)b * S_ + s) * C_ + c0);
    dst[xx] = (unsigned int)f2bf(tile[2 * xx][yy + k]) |
              ((unsigned int)f2bf(tile[2 * xx + 1][yy + k]) << 16);
  }
}

// ---------- R precompute: fp64 copy + split-bf16 MFMA-packed hi/lo ----------
// Packed layout: rpk[((a*8 + kc)*4 + mt)*64 + lane] -> 8 bf16, element q:
//   c = kc*32 + (lane>>4)*8 + q,  m = mt*16 + (lane&15)
__global__ __launch_bounds__(256) void cvt_r_kernel(const float* __restrict__ RM,
                                                    double* __restrict__ R64,
                                                    unsigned short* __restrict__ rpkhi,
                                                    unsigned short* __restrict__ rpklo) {
  int i = blockIdx.x * 256 + threadIdx.x;
  if (i >= A_ * C_ * 64) return;
  R64[i] = (double)RM[i];
  int q = i & 7, lane = (i >> 3) & 63, mt = (i >> 9) & 3, kc = (i >> 11) & 7, a = i >> 14;
  int c = kc * 32 + (lane >> 4) * 8 + q;
  int m = mt * 16 + (lane & 15);
  float r = RM[(a * C_ + c) * 64 + m];
  unsigned short hi = f2bf(r);
  unsigned short lo = f2bf(r - bf2f(hi));
  rpkhi[i] = hi;
  rpklo[i] = lo;
}

// ---------- hash: shared split-bf16 fragments + MFMA prescreen + fp64 refine ----------
// block = (b, 64 s); wave = a. X hi/lo converted ONCE per block into MFMA
// fragment layout FH/FL (A-frags shared by all 4 a-waves). Refine reads x
// from global (L2-hot). Keys identical to R16.
__global__ __launch_bounds__(256, 2) void hash_kernel(const float* __restrict__ in,
                                                      const double* __restrict__ R64,
                                                      const unsigned short* __restrict__ rpkhi,
                                                      const unsigned short* __restrict__ rpklo,
                                                      unsigned long long* __restrict__ keys) {
  __shared__ __align__(16) unsigned short FH[16384];  // 32 KB: [kc][st][lane][8]
  __shared__ __align__(16) unsigned short FL[16384];  // 32 KB
  __shared__ int cnt[A_ * 64];                        //  1 KB
  __shared__ short cand[A_ * 64 * 4];                 //  2 KB
  int blk = blockIdx.x;
  int chunk = blk % (S_ / 64);
  int b = blk / (S_ / 64);
  int s0 = chunk * 64;
  int tid = threadIdx.x;
  int a = __builtin_amdgcn_readfirstlane(tid >> 6);  // wave = hash round
  int lane = tid & 63, lr = lane & 15, lg = lane >> 4;

  for (int e = tid; e < A_ * 64; e += 256) cnt[e] = 0;
  // ---- stage + split-convert once (coalesced float4 along s) ----
  for (int e = tid; e < C_ * 16; e += 256) {
    int c = e >> 4, sq = (e & 15) << 2;
    float4 v = *(const float4*)&in[((size_t)b * C_ + c) * S_ + s0 + sq];
    int kc = c >> 5, lg2 = (c >> 3) & 3, q = c & 7;
#pragma unroll
    for (int i = 0; i < 4; ++i) {
      int s = sq + i;
      float xv = (&v.x)[i];
      unsigned short hi = f2bf(xv);
      unsigned short lo = f2bf(xv - bf2f(hi));
      int idx = ((kc * 4 + (s >> 4)) * 64 + ((s & 15) | (lg2 << 4))) * 8 + q;
      FH[idx] = hi;
      FL[idx] = lo;
    }
  }
  __syncthreads();

  // ---- prescreen: acc[st][mt] = P[s=st*16+lg*4+reg][m=mt*16+lr] ----
  f32x4 acc[4][4];
#pragma unroll
  for (int st = 0; st < 4; ++st)
#pragma unroll
    for (int mt = 0; mt < 4; ++mt) acc[st][mt] = (f32x4){0.f, 0.f, 0.f, 0.f};

  for (int kc = 0; kc < 8; ++kc) {
    bf16x8 ah[4], al[4];
#pragma unroll
    for (int st = 0; st < 4; ++st) {
      int base = ((kc * 4 + st) * 64 + lane) * 8;
      uint4 h = *(const uint4*)&FH[base];
      uint4 l = *(const uint4*)&FL[base];
      ah[st] = *(bf16x8*)&h;
      al[st] = *(bf16x8*)&l;
    }
    bf16x8 bh[4], bl[4];
#pragma unroll
    for (int mt = 0; mt < 4; ++mt) {
      size_t off = (size_t)(((a * 8 + kc) * 4 + mt) * 64 + lane) * 8;
      uint4 hv = *(const uint4*)(rpkhi + off);
      uint4 lv = *(const uint4*)(rpklo + off);
      bh[mt] = *(bf16x8*)&hv;
      bl[mt] = *(bf16x8*)&lv;
    }
#pragma unroll
    for (int st = 0; st < 4; ++st)
#pragma unroll
      for (int mt = 0; mt < 4; ++mt) {
        acc[st][mt] = MFMA(ah[st], bh[mt], acc[st][mt]);
        acc[st][mt] = MFMA(ah[st], bl[mt], acc[st][mt]);
        acc[st][mt] = MFMA(al[st], bh[mt], acc[st][mt]);
      }
  }

  // ---- per-s max over m, then mark candidates within thr ----
  const float thr = 1.5e-2f;
#pragma unroll
  for (int st = 0; st < 4; ++st) {
    f32x4 vmax;
#pragma unroll
    for (int reg = 0; reg < 4; ++reg) {
      float m0 = fmaxf(acc[st][0][reg], acc[st][1][reg]);
      float m1 = fmaxf(acc[st][2][reg], acc[st][3][reg]);
      vmax[reg] = fmaxf(m0, m1);
    }
#pragma unroll
    for (int off = 1; off < 16; off <<= 1)
#pragma unroll
      for (int reg = 0; reg < 4; ++reg)
        vmax[reg] = fmaxf(vmax[reg], __shfl_xor(vmax[reg], off));
#pragma unroll
    for (int reg = 0; reg < 4; ++reg) {
      int s = st * 16 + lg * 4 + reg;
      float cut = vmax[reg] - thr;
#pragma unroll
      for (int mt = 0; mt < 4; ++mt) {
        if (acc[st][mt][reg] >= cut) {
          int slot = atomicAdd(&cnt[a * 64 + s], 1);
          if (slot < 4) cand[(a * 64 + s) * 4 + slot] = (short)(mt * 16 + lr);
        }
      }
    }
  }
  __syncthreads();

  // ---- refine: lane = s; exact fp64 dot for each candidate (x from global) ----
  int s = lane;
  int n = cnt[a * 64 + s];
  n = n > 4 ? 4 : n;
  const double* __restrict__ Ra = R64 + (size_t)a * C_ * 64;
  const float* __restrict__ xcol = in + (size_t)b * C_ * S_ + s0 + s;
  double best = -1e300;
  for (int t = 0; t < n; ++t) {
    int m = cand[(a * 64 + s) * 4 + t];
    const double* __restrict__ Rm = Ra + m;
    double d0 = 0, d1 = 0, d2 = 0, d3 = 0;
#pragma unroll 2
    for (int c = 0; c < C_; c += 4) {
      d0 = fma((double)xcol[(size_t)(c + 0) * S_], Rm[(size_t)(c + 0) * 64], d0);
      d1 = fma((double)xcol[(size_t)(c + 1) * S_], Rm[(size_t)(c + 1) * 64], d1);
      d2 = fma((double)xcol[(size_t)(c + 2) * S_], Rm[(size_t)(c + 2) * 64], d2);
      d3 = fma((double)xcol[(size_t)(c + 3) * S_], Rm[(size_t)(c + 3) * 64], d3);
    }
    double d = (d0 + d1) + (d2 + d3);
    best = best > d ? best : d;
  }
  unsigned long long u = (unsigned long long)__double_as_longlong(best);
  unsigned long long mono = u ^ ((u >> 63) ? ~0ull : 0x8000000000000000ull);
  keys[((size_t)(b * A_ + a)) * SORTN + s0 + s] =
      (~mono & ~0x3FFFull) | (unsigned long long)(s0 + s);
}

// ---------- multi-block bitonic sort of 32 x 16384 keys ----------
__global__ __launch_bounds__(256) void pad_kernel(unsigned long long* __restrict__ keys) {
  int e = blockIdx.x * 256 + threadIdx.x;
  int ba = e / (SORTN - S_), off = e % (SORTN - S_);
  keys[(size_t)ba * SORTN + S_ + off] = ~0ull;
}

__global__ __launch_bounds__(256) void sort_local_kernel(unsigned long long* __restrict__ keys) {
  __shared__ unsigned long long lk[2048];
  int blk = blockIdx.x;
  int ba = blk >> 3, chunk = blk & 7;
  size_t base = (size_t)ba * SORTN + (size_t)chunk * 2048;
  int posbase = chunk * 2048;
  int tid = threadIdx.x;
  for (int i = tid; i < 2048; i += 256) lk[i] = keys[base + i];
  for (int k = 2; k <= 2048; k <<= 1)
    for (int j = k >> 1; j > 0; j >>= 1) {
      __syncthreads();
      for (int i = tid; i < 2048; i += 256) {
        int l = i ^ j;
        if (l > i) {
          unsigned long long a = lk[i], b = lk[l];
          bool up = (((posbase + i) & k) == 0);
          bool sw = up ? (a > b) : (a < b);
          if (sw) { lk[i] = b; lk[l] = a; }
        }
      }
    }
  __syncthreads();
  for (int i = tid; i < 2048; i += 256) keys[base + i] = lk[i];
}

template <int CS>
__global__ __launch_bounds__(512) void sort_merge_kernel(unsigned long long* __restrict__ keys,
                                                         int k, int startj) {
  __shared__ unsigned long long lk[CS];
  int blk = blockIdx.x;
  const int nch = SORTN / CS;
  int ba = blk / nch, chunk = blk % nch;
  size_t base = (size_t)ba * SORTN + (size_t)chunk * CS;
  int posbase = chunk * CS;
  int tid = threadIdx.x;
  for (int i = tid; i < CS; i += 512) lk[i] = keys[base + i];
  for (int j = startj; j > 0; j >>= 1) {
    __syncthreads();
    for (int i = tid; i < CS; i += 512) {
      int l = i ^ j;
      if (l > i) {
        unsigned long long a = lk[i], b = lk[l];
        bool up = (((posbase + i) & k) == 0);
        bool sw = up ? (a > b) : (a < b);
        if (sw) { lk[i] = b; lk[l] = a; }
      }
    }
  }
  __syncthreads();
  for (int i = tid; i < CS; i += 512) keys[base + i] = lk[i];
}

__global__ __launch_bounds__(256) void sort_gpass_kernel(unsigned long long* __restrict__ keys) {
  int e = blockIdx.x * 256 + threadIdx.x;
  int ba = e >> 13, p = e & 8191;
  size_t base = (size_t)ba * SORTN;
  unsigned long long a = keys[base + p], b = keys[base + p + 8192];
  if (a > b) {
    keys[base + p] = b;
    keys[base + p + 8192] = a;
  }
}

__global__ __launch_bounds__(512) void sort_final_kernel(const unsigned long long* __restrict__ keys,
                                                         int* __restrict__ idxs,
                                                         int* __restrict__ invs) {
  __shared__ unsigned long long lk[8192];
  int blk = blockIdx.x;
  int ba = blk >> 1, chunk = blk & 1;
  size_t base = (size_t)ba * SORTN + (size_t)chunk * 8192;
  int posbase = chunk * 8192;
  int tid = threadIdx.x;
  for (int i = tid; i < 8192; i += 512) lk[i] = keys[base + i];
  for (int j = 4096; j > 0; j >>= 1) {
    __syncthreads();
    for (int i = tid; i < 8192; i += 512) {
      int l = i ^ j;
      if (l > i) {
        unsigned long long a = lk[i], b = lk[l];
        if (a > b) { lk[i] = b; lk[l] = a; }
      }
    }
  }
  __syncthreads();
  int* ob = idxs + (size_t)ba * S_;
  int* iv = invs + (size_t)ba * S_;
  for (int i = tid; i < 8192; i += 512) {
    int pos = posbase + i;
    if (pos < S_) {
      int orig = (int)(lk[i] & 0x3FFFull);
      ob[pos] = orig;
      iv[orig] = pos;
    }
  }
}

// ---------- per-bucket MFMA attention, swapped-QK, 8 waves, 2 blocks/CU ----------
__global__ __launch_bounds__(512, 4) void attn_kernel(const unsigned short* __restrict__ xf16,
                                                      const float* __restrict__ in,
                                                      const int* __restrict__ idxs,
                                                      unsigned short* __restrict__ outacc,
                                                      float* __restrict__ out,
                                                      int use_xf, int path_a) {
  __shared__ __align__(16) unsigned short R1[K_ * 128];
  __shared__ __align__(16) unsigned short R2[128 * K_];
  __shared__ __align__(16) unsigned short Ps8[16 * 160];
  const int blk = blockIdx.x;
  const int r = blk & 63, a = (blk >> 6) & 3, b = blk >> 8;
  const int tid = threadIdx.x;
  const int w = __builtin_amdgcn_readfirstlane(tid >> 6);  // 0..7
  const int lane = tid & 63, lr = lane & 15, lg = lane >> 4;
  const int* __restrict__ idxr = idxs + ((size_t)(b * A_ + a)) * S_ + r * K_;
  const unsigned short* __restrict__ xfb = xf16 + (size_t)b * S_ * C_;
  const float scale = 0.0625f;  // 1/sqrt(256)

  auto stage = [&](int ch) {
    if (use_xf) {
      for (int e = tid; e < K_ * 16; e += 512) {
        int i = e >> 4, q8 = (e & 15) << 3;
        int s = idxr[i];
        uint4 d = *(const uint4*)(xfb + (size_t)s * C_ + ch * 128 + q8);
        *(uint4*)&R1[i * 128 + (q8 ^ ((i & 7) << 3))] = d;
      }
    } else {
      for (int e = tid; e < K_ * 128; e += 512) {
        int i = e >> 7, c = e & 127;
        R1[i * 128 + (c ^ ((i & 7) << 3))] =
            f2bf(in[((size_t)b * C_ + ch * 128 + c) * S_ + idxr[i]]);
      }
    }
  };

  auto transp = [&]() {
    int L = (tid & 7) | ((tid >> 8) << 3);
    int jb = (tid >> 3) & 31;
    if (jb < 18) {
      uint4 rv[8];
#pragma unroll
      for (int rr = 0; rr < 8; ++rr)
        rv[rr] = *(const uint4*)&R1[(jb * 8 + rr) * 128 + ((L * 8) ^ (rr << 3))];
#pragma unroll
      for (int cc = 0; cc < 8; ++cc) {
        unsigned int sel = (cc & 1) ? 0x07060302u : 0x05040100u;
        uint4 d;
        unsigned int* dd = (unsigned int*)&d;
#pragma unroll
        for (int q = 0; q < 4; ++q) {
          unsigned int lo = ((const unsigned int*)&rv[2 * q])[cc >> 1];
          unsigned int hi = ((const unsigned int*)&rv[2 * q + 1])[cc >> 1];
          dd[q] = __builtin_amdgcn_perm(hi, lo, sel);
        }
        *(uint4*)&R2[(L * 8 + cc) * K_ + jb * 8] = d;
      }
    }
  };

  for (int e = tid; e < 16 * 160 / 2; e += 512) ((unsigned int*)Ps8)[e] = 0u;
  stage(0);
  __syncthreads();

  f32x4 acc[9], acc8, acc8b;
#pragma unroll
  for (int jt = 0; jt < 9; ++jt) acc[jt] = (f32x4){0.f, 0.f, 0.f, 0.f};
  acc8 = (f32x4){0.f, 0.f, 0.f, 0.f};
  acc8b = (f32x4){0.f, 0.f, 0.f, 0.f};
  auto qk_half = [&]() {
    for (int kt = 0; kt < 4; ++kt) {
      int c0 = kt * 32 + lg * 8;
      int sw = c0 ^ ((lr & 7) << 3);
      bf16x8 fr[9];
#pragma unroll
      for (int jt = 0; jt < 9; ++jt)
        fr[jt] = *(const bf16x8*)&R1[(jt * 16 + lr) * 128 + sw];
      bf16x8 bT = *(const bf16x8*)&R1[(w * 16 + lr) * 128 + sw];
#pragma unroll
      for (int jt = 0; jt < 9; ++jt) acc[jt] = MFMA(fr[jt], bT, acc[jt]);
      acc8 = MFMA(bT, fr[8], acc8);
      if (w == 0) acc8b = MFMA(fr[8], fr[8], acc8b);
    }
  };
  qk_half();
  transp();
  __syncthreads();
  stage(1);
  __syncthreads();
  qk_half();

#pragma unroll
  for (int mm = 0; mm < 4; ++mm)
    Ps8[lr * 160 + (w * 16 + lg * 4 + mm)] = f2bf(acc8[mm]);
  if (w == 0) {
#pragma unroll
    for (int mm = 0; mm < 4; ++mm)
      Ps8[lr * 160 + (128 + lg * 4 + mm)] = f2bf(acc8b[mm]);
  }

  float mx = -1e30f;
#pragma unroll
  for (int jt = 0; jt < 9; ++jt)
#pragma unroll
    for (int mm = 0; mm < 4; ++mm) mx = fmaxf(mx, acc[jt][mm]);
  mx = fmaxf(mx, __shfl_xor(mx, 16));
  mx = fmaxf(mx, __shfl_xor(mx, 32));
  float sum = 0.f;
#pragma unroll
  for (int jt = 0; jt < 9; ++jt)
#pragma unroll
    for (int mm = 0; mm < 4; ++mm) {
      float e = __expf((acc[jt][mm] - mx) * scale);
      acc[jt][mm] = e;
      sum += e;
    }
  sum += __shfl_xor(sum, 16);
  sum += __shfl_xor(sum, 32);
  float inv = 1.0f / sum;
  unsigned int pk[18];
#pragma unroll
  for (int jt = 0; jt < 9; ++jt) {
    pk[2 * jt] = (unsigned int)f2bf(acc[jt][0] * inv) |
                 ((unsigned int)f2bf(acc[jt][1] * inv) << 16);
    pk[2 * jt + 1] = (unsigned int)f2bf(acc[jt][2] * inv) |
                     ((unsigned int)f2bf(acc[jt][3] * inv) << 16);
  }

  const int src1 = lr + 16 * ((2 * lg) & 3);
  const int src2 = lr + 16 * ((2 * lg + 1) & 3);
  const int hi8 = lg >> 1;
  bf16x8 pa[5];
#pragma unroll
  for (int kt = 0; kt < 5; ++kt) {
    const int jt0 = (kt < 4) ? 2 * kt : 7;
    unsigned int d0a = __shfl(pk[2 * jt0], src1), d0b = __shfl(pk[2 * jt0 + 2], src1);
    unsigned int d1a = __shfl(pk[2 * jt0 + 1], src1), d1b = __shfl(pk[2 * jt0 + 3], src1);
    unsigned int d2a = __shfl(pk[2 * jt0], src2), d2b = __shfl(pk[2 * jt0 + 2], src2);
    unsigned int d3a = __shfl(pk[2 * jt0 + 1], src2), d3b = __shfl(pk[2 * jt0 + 3], src2);
    uint4 d;
    d.x = hi8 ? d0b : d0a;
    d.y = hi8 ? d1b : d1a;
    d.z = hi8 ? d2b : d2a;
    d.w = hi8 ? d3b : d3a;
    if (kt == 4 && lg < 2) d = make_uint4(0u, 0u, 0u, 0u);
    pa[kt] = *(bf16x8*)&d;
  }
  __syncthreads();

  for (int rr = 0; rr < 2; ++rr) {
    int row = 2 * w + rr;
    float x0 = bf2f(Ps8[row * 160 + lane]);
    float x1 = bf2f(Ps8[row * 160 + 64 + lane]);
    float x2 = (lane < 16) ? bf2f(Ps8[row * 160 + 128 + lane]) : -1e30f;
    float m8 = fmaxf(fmaxf(x0, x1), x2);
    for (int off = 32; off; off >>= 1) m8 = fmaxf(m8, __shfl_xor(m8, off));
    float e0 = __expf((x0 - m8) * scale), e1 = __expf((x1 - m8) * scale);
    float e2 = (lane < 16) ? __expf((x2 - m8) * scale) : 0.f;
    float s8 = e0 + e1 + e2;
    for (int off = 32; off; off >>= 1) s8 += __shfl_xor(s8, off);
    float i8 = 1.0f / s8;
    Ps8[row * 160 + lane] = f2bf(e0 * i8);
    Ps8[row * 160 + 64 + lane] = f2bf(e1 * i8);
    if (lane < 16) Ps8[row * 160 + 128 + lane] = f2bf(e2 * i8);
  }
  __syncthreads();

  unsigned short* oaRow =
      path_a ? outacc + (((size_t)(b * A_ + a)) * S_ + (size_t)r * K_) * C_ : nullptr;
  auto pv_half = [&](int h) {
    f32x4 o[8], o8;
#pragma unroll
    for (int ct = 0; ct < 8; ++ct) o[ct] = (f32x4){0.f, 0.f, 0.f, 0.f};
    o8 = (f32x4){0.f, 0.f, 0.f, 0.f};
#pragma unroll
    for (int kt = 0; kt < 5; ++kt) {
      int J0 = (kt < 4) ? kt * 32 : 112;
      int j8 = (kt < 4) ? (J0 + lg * 8) : ((lg < 2) ? (144 + lg * 8) : (112 + lg * 8));
      bf16x8 pa8 = *(const bf16x8*)&Ps8[lr * 160 + j8];
#pragma unroll
      for (int ct = 0; ct < 8; ++ct) {
        bf16x8 vb = *(const bf16x8*)&R2[(ct * 16 + lr) * K_ + J0 + lg * 8];
        o[ct] = MFMA(pa[kt], vb, o[ct]);
        if (ct == w) o8 = MFMA(pa8, vb, o8);
      }
    }
    if (path_a) {
#pragma unroll
      for (int ct = 0; ct < 8; ++ct) {
        int cg = h * 128 + ct * 16 + lr;
#pragma unroll
        for (int rr = 0; rr < 4; ++rr) {
          int i = w * 16 + lg * 4 + rr;
          oaRow[(size_t)i * C_ + cg] = f2bf(o[ct][rr]);
        }
      }
      int cg8 = h * 128 + w * 16 + lr;
#pragma unroll
      for (int rr = 0; rr < 4; ++rr)
        oaRow[(size_t)(128 + lg * 4 + rr) * C_ + cg8] = f2bf(o8[rr]);
    } else {
#pragma unroll
      for (int ct = 0; ct < 8; ++ct) {
        int cg = h * 128 + ct * 16 + lr;
#pragma unroll
        for (int rr = 0; rr < 4; ++rr) {
          int s = idxr[w * 16 + lg * 4 + rr];
          atomicAdd(&out[((size_t)b * S_ + s) * C_ + cg], o[ct][rr] * 0.25f);
        }
      }
      int cg8 = h * 128 + w * 16 + lr;
#pragma unroll
      for (int rr = 0; rr < 4; ++rr) {
        int s = idxr[128 + lg * 4 + rr];
        atomicAdd(&out[((size_t)b * S_ + s) * C_ + cg8], o8[rr] * 0.25f);
      }
    }
  };

  pv_half(0);
  __syncthreads();
  transp();
  __syncthreads();
  pv_half(1);
}

// ---------- gather-reduce: out[b][s][c] = 1/4 sum_a outacc[b][a][inv[a][s]][c] ----------
__global__ __launch_bounds__(256) void reduce_kernel(const unsigned short* __restrict__ outacc,
                                                     const int* __restrict__ invs,
                                                     float* __restrict__ out) {
  size_t i = (size_t)blockIdx.x * 256 + threadIdx.x;
  size_t n4 = (size_t)B_ * S_ * C_ / 4;
  if (i >= n4) return;
  int cq = (int)(i & (C_ / 4 - 1));
  size_t bs = i >> 6;
  int s = (int)(bs % S_);
  int b = (int)(bs / S_);
  float4 sum = make_float4(0.f, 0.f, 0.f, 0.f);
#pragma unroll
  for (int a = 0; a < A_; ++a) {
    size_t base = (size_t)(b * A_ + a) * S_;
    int p = invs[base + s];
    ushort4 v = *(const ushort4*)(outacc + (base + p) * C_ + cq * 4);
    sum.x += bf2f(v.x);
    sum.y += bf2f(v.y);
    sum.z += bf2f(v.z);
    sum.w += bf2f(v.w);
  }
  float4 rv = make_float4(sum.x * 0.25f, sum.y * 0.25f, sum.z * 0.25f, sum.w * 0.25f);
  *(float4*)(out + ((size_t)b * S_ + s) * C_ + cq * 4) = rv;
}

__global__ __launch_bounds__(256) void zero_kernel(float* __restrict__ out) {
  size_t i = (size_t)blockIdx.x * 256 + threadIdx.x;
  size_t n4 = (size_t)B_ * S_ * C_ / 4;
  if (i >= n4) return;
  *(float4*)(out + i * 4) = make_float4(0.f, 0.f, 0.f, 0.f);
}

extern "C" void kernel_launch(void* const* d_in, const int* in_sizes, int n_in,
                              void* d_out, int out_size, void* d_ws, size_t ws_size,
                              hipStream_t stream) {
  const float* in = (const float*)d_in[0];
  const float* RM = (const float*)d_in[1];
  float* out = (float*)d_out;
  const size_t r64_b  = (size_t)A_ * C_ * 64 * 8;        //   0.5 MB
  const size_t rpk_b  = (size_t)A_ * C_ * 64 * 2;        //   128 KB (each)
  const size_t key_b  = (size_t)B_ * A_ * SORTN * 8;     //   4.19 MB
  const size_t idx_b  = (size_t)B_ * A_ * S_ * 4;        //   1.18 MB
  const size_t inv_b  = (size_t)B_ * A_ * S_ * 4;        //   1.18 MB
  const size_t xf_b   = (size_t)B_ * S_ * C_ * 2;        //  37.7 MB (bf16)
  const size_t accw_b = (size_t)B_ * A_ * S_ * C_ * 2;   // 151 MB (bf16)
  char* ws = (char*)d_ws;
  size_t off = 0;
  double* R64 = (double*)(ws + off); off += r64_b;
  unsigned short* rpkhi = (unsigned short*)(ws + off); off += rpk_b;
  unsigned short* rpklo = (unsigned short*)(ws + off); off += rpk_b;
  unsigned long long* keys = (unsigned long long*)(ws + off); off += key_b;
  int* idxs = (int*)(ws + off); off += idx_b;
  int* invs = (int*)(ws + off); off += inv_b;
  int use_xf = ws_size >= off + xf_b;
  unsigned short* xf16 = nullptr;
  if (use_xf) { xf16 = (unsigned short*)(ws + off); off += xf_b; }
  int path_a = ws_size >= off + accw_b;
  unsigned short* outacc = nullptr;
  if (path_a) { outacc = (unsigned short*)(ws + off); off += accw_b; }

  cvt_r_kernel<<<dim3((A_ * C_ * 64 + 255) / 256), 256, 0, stream>>>(RM, R64, rpkhi, rpklo);
  if (use_xf)
    t_kernel<<<dim3(S_ / 32, C_ / 32, B_), 256, 0, stream>>>(in, xf16);
  hash_kernel<<<dim3(B_ * (S_ / 64)), 256, 0, stream>>>(in, R64, rpkhi, rpklo, keys);
  // ---- multi-block bitonic sort ----
  pad_kernel<<<dim3(B_ * A_ * (SORTN - S_) / 256), 256, 0, stream>>>(keys);
  sort_local_kernel<<<dim3(B_ * A_ * 8), 256, 0, stream>>>(keys);
  sort_merge_kernel<4096><<<dim3(B_ * A_ * 4), 512, 0, stream>>>(keys, 4096, 2048);
  sort_merge_kernel<8192><<<dim3(B_ * A_ * 2), 512, 0, stream>>>(keys, 8192, 4096);
  sort_gpass_kernel<<<dim3(B_ * A_ * 8192 / 256), 256, 0, stream>>>(keys);
  sort_final_kernel<<<dim3(B_ * A_ * 2), 512, 0, stream>>>(keys, idxs, invs);

  size_t n4 = (size_t)B_ * S_ * C_ / 4;
  int rb = (int)((n4 + 255) / 256);
  if (!path_a) zero_kernel<<<dim3(rb), 256, 0, stream>>>(out);
  attn_kernel<<<dim3(B_ * A_ * NB_), 512, 0, stream>>>(xf16, in, idxs, outacc, out, use_xf, path_a);
  if (path_a) reduce_kernel<<<dim3(rb), 256, 0, stream>>>(outacc, invs, out);
}

// Round 19
// 429.330 us; speedup vs baseline: 1.0815x; 1.0815x over previous
//
#include <hip/hip_runtime.h>
#include <math.h>

#define B_ 8
#define C_ 256
#define S_ 9216
#define A_ 4
#define K_ 144
#define NB_ 64
#define SORTN 16384
#define XSS 261  // hash Xs row stride (float): odd, ==5 mod 32 -> conflict-free

typedef __bf16 bf16x8 __attribute__((ext_vector_type(8)));
typedef float f32x4 __attribute__((ext_vector_type(4)));
#define MFMA(a, b, c) __builtin_amdgcn_mfma_f32_16x16x32_bf16(a, b, c, 0, 0, 0)

// bf16 round-to-nearest-even
__device__ __forceinline__ unsigned short f2bf(float f) {
  unsigned int u = __float_as_uint(f);
  u = (u + 0x7FFFu + ((u >> 16) & 1u)) >> 16;
  return (unsigned short)u;
}
__device__ __forceinline__ float bf2f(unsigned short u) {
  return __uint_as_float(((unsigned int)u) << 16);
}

// ---------- transpose+convert: xf16[b][s][c] = bf16(in[b][c][s]) ----------
__global__ __launch_bounds__(256) void t_kernel(const float* __restrict__ in,
                                                unsigned short* __restrict__ xf16) {
  __shared__ float tile[32][33];
  int b = blockIdx.z;
  int c0 = blockIdx.y << 5, s0 = blockIdx.x << 5;
  int x = threadIdx.x & 31, y = threadIdx.x >> 5;  // 32 x 8
  const float* ip = in + ((size_t)b * C_ + c0 + y) * S_ + s0 + x;
#pragma unroll
  for (int k = 0; k < 32; k += 8) tile[y + k][x] = ip[(size_t)k * S_];
  __syncthreads();
  int xx = threadIdx.x & 15;        // c-pair 0..15 (32 c per tile)
  int yy = threadIdx.x >> 4;        // s row 0..15; two passes
#pragma unroll
  for (int k = 0; k < 32; k += 16) {
    int s = s0 + yy + k;
    unsigned int* dst = (unsigned int*)(xf16 + ((size_t)b * S_ + s) * C_ + c0);
    dst[xx] = (unsigned int)f2bf(tile[2 * xx][yy + k]) |
              ((unsigned int)f2bf(tile[2 * xx + 1][yy + k]) << 16);
  }
}

// ---------- R precompute: fp64 copy + split-bf16 MFMA-packed hi/lo ----------
// Packed layout: rpk[((a*8 + kc)*4 + mt)*64 + lane] -> 8 bf16, element q:
//   c = kc*32 + (lane>>4)*8 + q,  m = mt*16 + (lane&15)
__global__ __launch_bounds__(256) void cvt_r_kernel(const float* __restrict__ RM,
                                                    double* __restrict__ R64,
                                                    unsigned short* __restrict__ rpkhi,
                                                    unsigned short* __restrict__ rpklo) {
  int i = blockIdx.x * 256 + threadIdx.x;
  if (i >= A_ * C_ * 64) return;
  R64[i] = (double)RM[i];
  int q = i & 7, lane = (i >> 3) & 63, mt = (i >> 9) & 3, kc = (i >> 11) & 7, a = i >> 14;
  int c = kc * 32 + (lane >> 4) * 8 + q;
  int m = mt * 16 + (lane & 15);
  float r = RM[(a * C_ + c) * 64 + m];
  unsigned short hi = f2bf(r);
  unsigned short lo = f2bf(r - bf2f(hi));
  rpkhi[i] = hi;
  rpklo[i] = lo;
}

// ---------- hash: split-bf16 MFMA prescreen + sparse fp64 refine (R16) ----------
__global__ __launch_bounds__(256, 2) void hash_kernel(const float* __restrict__ in,
                                                      const double* __restrict__ R64,
                                                      const unsigned short* __restrict__ rpkhi,
                                                      const unsigned short* __restrict__ rpklo,
                                                      unsigned long long* __restrict__ keys) {
  __shared__ float Xs[64 * XSS];      // 66816 B
  __shared__ int cnt[A_ * 64];        //  1024 B
  __shared__ short cand[A_ * 64 * 4]; //  2048 B
  int blk = blockIdx.x;
  int chunk = blk % (S_ / 64);
  int b = blk / (S_ / 64);
  int s0 = chunk * 64;
  int tid = threadIdx.x;
  int a = __builtin_amdgcn_readfirstlane(tid >> 6);  // wave = hash round
  int lane = tid & 63, lr = lane & 15, lg = lane >> 4;

  for (int e = tid; e < A_ * 64; e += 256) cnt[e] = 0;
  // ---- stage Xs[s][c] = in[b][c][s0+s] (float4 along s, scatter to LDS) ----
  for (int e = tid; e < C_ * 16; e += 256) {
    int c = e >> 4, sq = (e & 15) << 2;
    float4 v = *(const float4*)&in[((size_t)b * C_ + c) * S_ + s0 + sq];
    Xs[(sq + 0) * XSS + c] = v.x;
    Xs[(sq + 1) * XSS + c] = v.y;
    Xs[(sq + 2) * XSS + c] = v.z;
    Xs[(sq + 3) * XSS + c] = v.w;
  }
  __syncthreads();

  // ---- prescreen: acc[st][mt] = P[s=st*16+lg*4+reg][m=mt*16+lr] ----
  f32x4 acc[4][4];
#pragma unroll
  for (int st = 0; st < 4; ++st)
#pragma unroll
    for (int mt = 0; mt < 4; ++mt) acc[st][mt] = (f32x4){0.f, 0.f, 0.f, 0.f};

  for (int kc = 0; kc < 8; ++kc) {
    bf16x8 ahi[4], alo[4];
#pragma unroll
    for (int st = 0; st < 4; ++st) {
      ushort hs[8], ls[8];
#pragma unroll
      for (int q = 0; q < 8; ++q) {
        float xv = Xs[(st * 16 + lr) * XSS + kc * 32 + lg * 8 + q];
        hs[q] = f2bf(xv);
        ls[q] = f2bf(xv - bf2f(hs[q]));
      }
      uint4 hu, lu;
      hu.x = hs[0] | ((unsigned)hs[1] << 16); hu.y = hs[2] | ((unsigned)hs[3] << 16);
      hu.z = hs[4] | ((unsigned)hs[5] << 16); hu.w = hs[6] | ((unsigned)hs[7] << 16);
      lu.x = ls[0] | ((unsigned)ls[1] << 16); lu.y = ls[2] | ((unsigned)ls[3] << 16);
      lu.z = ls[4] | ((unsigned)ls[5] << 16); lu.w = ls[6] | ((unsigned)ls[7] << 16);
      ahi[st] = *(bf16x8*)&hu;
      alo[st] = *(bf16x8*)&lu;
    }
    bf16x8 bh[4], bl[4];
#pragma unroll
    for (int mt = 0; mt < 4; ++mt) {
      size_t off = (size_t)(((a * 8 + kc) * 4 + mt) * 64 + lane) * 8;
      uint4 hv = *(const uint4*)(rpkhi + off);
      uint4 lv = *(const uint4*)(rpklo + off);
      bh[mt] = *(bf16x8*)&hv;
      bl[mt] = *(bf16x8*)&lv;
    }
#pragma unroll
    for (int st = 0; st < 4; ++st)
#pragma unroll
      for (int mt = 0; mt < 4; ++mt) {
        acc[st][mt] = MFMA(ahi[st], bh[mt], acc[st][mt]);
        acc[st][mt] = MFMA(ahi[st], bl[mt], acc[st][mt]);
        acc[st][mt] = MFMA(alo[st], bh[mt], acc[st][mt]);
      }
  }

  // ---- per-s max over m, then mark candidates within thr ----
  const float thr = 1.5e-2f;
#pragma unroll
  for (int st = 0; st < 4; ++st) {
    f32x4 vmax;
#pragma unroll
    for (int reg = 0; reg < 4; ++reg) {
      float m0 = fmaxf(acc[st][0][reg], acc[st][1][reg]);
      float m1 = fmaxf(acc[st][2][reg], acc[st][3][reg]);
      vmax[reg] = fmaxf(m0, m1);
    }
#pragma unroll
    for (int off = 1; off < 16; off <<= 1)
#pragma unroll
      for (int reg = 0; reg < 4; ++reg)
        vmax[reg] = fmaxf(vmax[reg], __shfl_xor(vmax[reg], off));
#pragma unroll
    for (int reg = 0; reg < 4; ++reg) {
      int s = st * 16 + lg * 4 + reg;
      float cut = vmax[reg] - thr;
#pragma unroll
      for (int mt = 0; mt < 4; ++mt) {
        if (acc[st][mt][reg] >= cut) {
          int slot = atomicAdd(&cnt[a * 64 + s], 1);
          if (slot < 4) cand[(a * 64 + s) * 4 + slot] = (short)(mt * 16 + lr);
        }
      }
    }
  }
  __syncthreads();

  // ---- refine: lane = s; exact fp64 dot for each candidate ----
  int s = lane;
  int n = cnt[a * 64 + s];
  n = n > 4 ? 4 : n;
  const double* __restrict__ Ra = R64 + (size_t)a * C_ * 64;
  double best = -1e300;
  for (int t = 0; t < n; ++t) {
    int m = cand[(a * 64 + s) * 4 + t];
    const double* __restrict__ Rm = Ra + m;
    double d0 = 0, d1 = 0, d2 = 0, d3 = 0;
#pragma unroll 2
    for (int c = 0; c < C_; c += 4) {
      d0 = fma((double)Xs[s * XSS + c + 0], Rm[(size_t)(c + 0) * 64], d0);
      d1 = fma((double)Xs[s * XSS + c + 1], Rm[(size_t)(c + 1) * 64], d1);
      d2 = fma((double)Xs[s * XSS + c + 2], Rm[(size_t)(c + 2) * 64], d2);
      d3 = fma((double)Xs[s * XSS + c + 3], Rm[(size_t)(c + 3) * 64], d3);
    }
    double d = (d0 + d1) + (d2 + d3);
    best = best > d ? best : d;
  }
  unsigned long long u = (unsigned long long)__double_as_longlong(best);
  unsigned long long mono = u ^ ((u >> 63) ? ~0ull : 0x8000000000000000ull);
  keys[((size_t)(b * A_ + a)) * SORTN + s0 + s] =
      (~mono & ~0x3FFFull) | (unsigned long long)(s0 + s);
}

// ---------- multi-block bitonic sort of 32 x 16384 keys ----------
__global__ __launch_bounds__(256) void pad_kernel(unsigned long long* __restrict__ keys) {
  int e = blockIdx.x * 256 + threadIdx.x;
  int ba = e / (SORTN - S_), off = e % (SORTN - S_);
  keys[(size_t)ba * SORTN + S_ + off] = ~0ull;
}

__global__ __launch_bounds__(256) void sort_local_kernel(unsigned long long* __restrict__ keys) {
  __shared__ unsigned long long lk[2048];
  int blk = blockIdx.x;
  int ba = blk >> 3, chunk = blk & 7;
  size_t base = (size_t)ba * SORTN + (size_t)chunk * 2048;
  int posbase = chunk * 2048;
  int tid = threadIdx.x;
  for (int i = tid; i < 2048; i += 256) lk[i] = keys[base + i];
  for (int k = 2; k <= 2048; k <<= 1)
    for (int j = k >> 1; j > 0; j >>= 1) {
      __syncthreads();
      for (int i = tid; i < 2048; i += 256) {
        int l = i ^ j;
        if (l > i) {
          unsigned long long a = lk[i], b = lk[l];
          bool up = (((posbase + i) & k) == 0);
          bool sw = up ? (a > b) : (a < b);
          if (sw) { lk[i] = b; lk[l] = a; }
        }
      }
    }
  __syncthreads();
  for (int i = tid; i < 2048; i += 256) keys[base + i] = lk[i];
}

template <int CS>
__global__ __launch_bounds__(512) void sort_merge_kernel(unsigned long long* __restrict__ keys,
                                                         int k, int startj) {
  __shared__ unsigned long long lk[CS];
  int blk = blockIdx.x;
  const int nch = SORTN / CS;
  int ba = blk / nch, chunk = blk % nch;
  size_t base = (size_t)ba * SORTN + (size_t)chunk * CS;
  int posbase = chunk * CS;
  int tid = threadIdx.x;
  for (int i = tid; i < CS; i += 512) lk[i] = keys[base + i];
  for (int j = startj; j > 0; j >>= 1) {
    __syncthreads();
    for (int i = tid; i < CS; i += 512) {
      int l = i ^ j;
      if (l > i) {
        unsigned long long a = lk[i], b = lk[l];
        bool up = (((posbase + i) & k) == 0);
        bool sw = up ? (a > b) : (a < b);
        if (sw) { lk[i] = b; lk[l] = a; }
      }
    }
  }
  __syncthreads();
  for (int i = tid; i < CS; i += 512) keys[base + i] = lk[i];
}

__global__ __launch_bounds__(256) void sort_gpass_kernel(unsigned long long* __restrict__ keys) {
  int e = blockIdx.x * 256 + threadIdx.x;
  int ba = e >> 13, p = e & 8191;
  size_t base = (size_t)ba * SORTN;
  unsigned long long a = keys[base + p], b = keys[base + p + 8192];
  if (a > b) {
    keys[base + p] = b;
    keys[base + p + 8192] = a;
  }
}

__global__ __launch_bounds__(512) void sort_final_kernel(const unsigned long long* __restrict__ keys,
                                                         int* __restrict__ idxs,
                                                         int* __restrict__ invs) {
  __shared__ unsigned long long lk[8192];
  int blk = blockIdx.x;
  int ba = blk >> 1, chunk = blk & 1;
  size_t base = (size_t)ba * SORTN + (size_t)chunk * 8192;
  int posbase = chunk * 8192;
  int tid = threadIdx.x;
  for (int i = tid; i < 8192; i += 512) lk[i] = keys[base + i];
  for (int j = 4096; j > 0; j >>= 1) {
    __syncthreads();
    for (int i = tid; i < 8192; i += 512) {
      int l = i ^ j;
      if (l > i) {
        unsigned long long a = lk[i], b = lk[l];
        if (a > b) { lk[i] = b; lk[l] = a; }
      }
    }
  }
  __syncthreads();
  int* ob = idxs + (size_t)ba * S_;
  int* iv = invs + (size_t)ba * S_;
  for (int i = tid; i < 8192; i += 512) {
    int pos = posbase + i;
    if (pos < S_) {
      int orig = (int)(lk[i] & 0x3FFFull);
      ob[pos] = orig;
      iv[orig] = pos;
    }
  }
}

// ---------- per-bucket MFMA attention, swapped-QK, 8 waves, 2 blocks/CU ----------
// XCD-chunked swizzle: blk = ((bid&7)<<8)|(bid>>3) -> XCD x handles batch b=x,
// so each XCD's private L2 holds mostly one 4.7 MB xf16 slice.
__global__ __launch_bounds__(512, 4) void attn_kernel(const unsigned short* __restrict__ xf16,
                                                      const float* __restrict__ in,
                                                      const int* __restrict__ idxs,
                                                      unsigned short* __restrict__ outacc,
                                                      float* __restrict__ out,
                                                      int use_xf, int path_a) {
  __shared__ __align__(16) unsigned short R1[K_ * 128];
  __shared__ __align__(16) unsigned short R2[128 * K_];
  __shared__ __align__(16) unsigned short Ps8[16 * 160];
  const int bid = blockIdx.x;
  const int blk = ((bid & 7) << 8) | (bid >> 3);  // bijective: 2048 % 8 == 0
  const int r = blk & 63, a = (blk >> 6) & 3, b = blk >> 8;
  const int tid = threadIdx.x;
  const int w = __builtin_amdgcn_readfirstlane(tid >> 6);  // 0..7
  const int lane = tid & 63, lr = lane & 15, lg = lane >> 4;
  const int* __restrict__ idxr = idxs + ((size_t)(b * A_ + a)) * S_ + r * K_;
  const unsigned short* __restrict__ xfb = xf16 + (size_t)b * S_ * C_;
  const float scale = 0.0625f;  // 1/sqrt(256)

  auto stage = [&](int ch) {
    if (use_xf) {
      for (int e = tid; e < K_ * 16; e += 512) {
        int i = e >> 4, q8 = (e & 15) << 3;
        int s = idxr[i];
        uint4 d = *(const uint4*)(xfb + (size_t)s * C_ + ch * 128 + q8);
        *(uint4*)&R1[i * 128 + (q8 ^ ((i & 7) << 3))] = d;
      }
    } else {
      for (int e = tid; e < K_ * 128; e += 512) {
        int i = e >> 7, c = e & 127;
        R1[i * 128 + (c ^ ((i & 7) << 3))] =
            f2bf(in[((size_t)b * C_ + ch * 128 + c) * S_ + idxr[i]]);
      }
    }
  };

  auto transp = [&]() {
    int L = (tid & 7) | ((tid >> 8) << 3);
    int jb = (tid >> 3) & 31;
    if (jb < 18) {
      uint4 rv[8];
#pragma unroll
      for (int rr = 0; rr < 8; ++rr)
        rv[rr] = *(const uint4*)&R1[(jb * 8 + rr) * 128 + ((L * 8) ^ (rr << 3))];
#pragma unroll
      for (int cc = 0; cc < 8; ++cc) {
        unsigned int sel = (cc & 1) ? 0x07060302u : 0x05040100u;
        uint4 d;
        unsigned int* dd = (unsigned int*)&d;
#pragma unroll
        for (int q = 0; q < 4; ++q) {
          unsigned int lo = ((const unsigned int*)&rv[2 * q])[cc >> 1];
          unsigned int hi = ((const unsigned int*)&rv[2 * q + 1])[cc >> 1];
          dd[q] = __builtin_amdgcn_perm(hi, lo, sel);
        }
        *(uint4*)&R2[(L * 8 + cc) * K_ + jb * 8] = d;
      }
    }
  };

  for (int e = tid; e < 16 * 160 / 2; e += 512) ((unsigned int*)Ps8)[e] = 0u;
  stage(0);
  __syncthreads();

  f32x4 acc[9], acc8, acc8b;
#pragma unroll
  for (int jt = 0; jt < 9; ++jt) acc[jt] = (f32x4){0.f, 0.f, 0.f, 0.f};
  acc8 = (f32x4){0.f, 0.f, 0.f, 0.f};
  acc8b = (f32x4){0.f, 0.f, 0.f, 0.f};
  auto qk_half = [&]() {
    for (int kt = 0; kt < 4; ++kt) {
      int c0 = kt * 32 + lg * 8;
      int sw = c0 ^ ((lr & 7) << 3);
      bf16x8 fr[9];
#pragma unroll
      for (int jt = 0; jt < 9; ++jt)
        fr[jt] = *(const bf16x8*)&R1[(jt * 16 + lr) * 128 + sw];
      bf16x8 bT = *(const bf16x8*)&R1[(w * 16 + lr) * 128 + sw];
#pragma unroll
      for (int jt = 0; jt < 9; ++jt) acc[jt] = MFMA(fr[jt], bT, acc[jt]);
      acc8 = MFMA(bT, fr[8], acc8);
      if (w == 0) acc8b = MFMA(fr[8], fr[8], acc8b);
    }
  };
  qk_half();
  transp();
  __syncthreads();
  stage(1);
  __syncthreads();
  qk_half();

#pragma unroll
  for (int mm = 0; mm < 4; ++mm)
    Ps8[lr * 160 + (w * 16 + lg * 4 + mm)] = f2bf(acc8[mm]);
  if (w == 0) {
#pragma unroll
    for (int mm = 0; mm < 4; ++mm)
      Ps8[lr * 160 + (128 + lg * 4 + mm)] = f2bf(acc8b[mm]);
  }

  float mx = -1e30f;
#pragma unroll
  for (int jt = 0; jt < 9; ++jt)
#pragma unroll
    for (int mm = 0; mm < 4; ++mm) mx = fmaxf(mx, acc[jt][mm]);
  mx = fmaxf(mx, __shfl_xor(mx, 16));
  mx = fmaxf(mx, __shfl_xor(mx, 32));
  float sum = 0.f;
#pragma unroll
  for (int jt = 0; jt < 9; ++jt)
#pragma unroll
    for (int mm = 0; mm < 4; ++mm) {
      float e = __expf((acc[jt][mm] - mx) * scale);
      acc[jt][mm] = e;
      sum += e;
    }
  sum += __shfl_xor(sum, 16);
  sum += __shfl_xor(sum, 32);
  float inv = 1.0f / sum;
  unsigned int pk[18];
#pragma unroll
  for (int jt = 0; jt < 9; ++jt) {
    pk[2 * jt] = (unsigned int)f2bf(acc[jt][0] * inv) |
                 ((unsigned int)f2bf(acc[jt][1] * inv) << 16);
    pk[2 * jt + 1] = (unsigned int)f2bf(acc[jt][2] * inv) |
                     ((unsigned int)f2bf(acc[jt][3] * inv) << 16);
  }

  const int src1 = lr + 16 * ((2 * lg) & 3);
  const int src2 = lr + 16 * ((2 * lg + 1) & 3);
  const int hi8 = lg >> 1;
  bf16x8 pa[5];
#pragma unroll
  for (int kt = 0; kt < 5; ++kt) {
    const int jt0 = (kt < 4) ? 2 * kt : 7;
    unsigned int d0a = __shfl(pk[2 * jt0], src1), d0b = __shfl(pk[2 * jt0 + 2], src1);
    unsigned int d1a = __shfl(pk[2 * jt0 + 1], src1), d1b = __shfl(pk[2 * jt0 + 3], src1);
    unsigned int d2a = __shfl(pk[2 * jt0], src2), d2b = __shfl(pk[2 * jt0 + 2], src2);
    unsigned int d3a = __shfl(pk[2 * jt0 + 1], src2), d3b = __shfl(pk[2 * jt0 + 3], src2);
    uint4 d;
    d.x = hi8 ? d0b : d0a;
    d.y = hi8 ? d1b : d1a;
    d.z = hi8 ? d2b : d2a;
    d.w = hi8 ? d3b : d3a;
    if (kt == 4 && lg < 2) d = make_uint4(0u, 0u, 0u, 0u);
    pa[kt] = *(bf16x8*)&d;
  }
  __syncthreads();

  for (int rr = 0; rr < 2; ++rr) {
    int row = 2 * w + rr;
    float x0 = bf2f(Ps8[row * 160 + lane]);
    float x1 = bf2f(Ps8[row * 160 + 64 + lane]);
    float x2 = (lane < 16) ? bf2f(Ps8[row * 160 + 128 + lane]) : -1e30f;
    float m8 = fmaxf(fmaxf(x0, x1), x2);
    for (int off = 32; off; off >>= 1) m8 = fmaxf(m8, __shfl_xor(m8, off));
    float e0 = __expf((x0 - m8) * scale), e1 = __expf((x1 - m8) * scale);
    float e2 = (lane < 16) ? __expf((x2 - m8) * scale) : 0.f;
    float s8 = e0 + e1 + e2;
    for (int off = 32; off; off >>= 1) s8 += __shfl_xor(s8, off);
    float i8 = 1.0f / s8;
    Ps8[row * 160 + lane] = f2bf(e0 * i8);
    Ps8[row * 160 + 64 + lane] = f2bf(e1 * i8);
    if (lane < 16) Ps8[row * 160 + 128 + lane] = f2bf(e2 * i8);
  }
  __syncthreads();

  unsigned short* oaRow =
      path_a ? outacc + (((size_t)(b * A_ + a)) * S_ + (size_t)r * K_) * C_ : nullptr;
  auto pv_half = [&](int h) {
    f32x4 o[8], o8;
#pragma unroll
    for (int ct = 0; ct < 8; ++ct) o[ct] = (f32x4){0.f, 0.f, 0.f, 0.f};
    o8 = (f32x4){0.f, 0.f, 0.f, 0.f};
#pragma unroll
    for (int kt = 0; kt < 5; ++kt) {
      int J0 = (kt < 4) ? kt * 32 : 112;
      int j8 = (kt < 4) ? (J0 + lg * 8) : ((lg < 2) ? (144 + lg * 8) : (112 + lg * 8));
      bf16x8 pa8 = *(const bf16x8*)&Ps8[lr * 160 + j8];
#pragma unroll
      for (int ct = 0; ct < 8; ++ct) {
        bf16x8 vb = *(const bf16x8*)&R2[(ct * 16 + lr) * K_ + J0 + lg * 8];
        o[ct] = MFMA(pa[kt], vb, o[ct]);
        if (ct == w) o8 = MFMA(pa8, vb, o8);
      }
    }
    if (path_a) {
#pragma unroll
      for (int ct = 0; ct < 8; ++ct) {
        int cg = h * 128 + ct * 16 + lr;
#pragma unroll
        for (int rr = 0; rr < 4; ++rr) {
          int i = w * 16 + lg * 4 + rr;
          oaRow[(size_t)i * C_ + cg] = f2bf(o[ct][rr]);
        }
      }
      int cg8 = h * 128 + w * 16 + lr;
#pragma unroll
      for (int rr = 0; rr < 4; ++rr)
        oaRow[(size_t)(128 + lg * 4 + rr) * C_ + cg8] = f2bf(o8[rr]);
    } else {
#pragma unroll
      for (int ct = 0; ct < 8; ++ct) {
        int cg = h * 128 + ct * 16 + lr;
#pragma unroll
        for (int rr = 0; rr < 4; ++rr) {
          int s = idxr[w * 16 + lg * 4 + rr];
          atomicAdd(&out[((size_t)b * S_ + s) * C_ + cg], o[ct][rr] * 0.25f);
        }
      }
      int cg8 = h * 128 + w * 16 + lr;
#pragma unroll
      for (int rr = 0; rr < 4; ++rr) {
        int s = idxr[128 + lg * 4 + rr];
        atomicAdd(&out[((size_t)b * S_ + s) * C_ + cg8], o8[rr] * 0.25f);
      }
    }
  };

  pv_half(0);
  __syncthreads();
  transp();
  __syncthreads();
  pv_half(1);
}

// ---------- gather-reduce: out[b][s][c] = 1/4 sum_a outacc[b][a][inv[a][s]][c] ----------
__global__ __launch_bounds__(256) void reduce_kernel(const unsigned short* __restrict__ outacc,
                                                     const int* __restrict__ invs,
                                                     float* __restrict__ out) {
  size_t i = (size_t)blockIdx.x * 256 + threadIdx.x;
  size_t n4 = (size_t)B_ * S_ * C_ / 4;
  if (i >= n4) return;
  int cq = (int)(i & (C_ / 4 - 1));
  size_t bs = i >> 6;
  int s = (int)(bs % S_);
  int b = (int)(bs / S_);
  float4 sum = make_float4(0.f, 0.f, 0.f, 0.f);
#pragma unroll
  for (int a = 0; a < A_; ++a) {
    size_t base = (size_t)(b * A_ + a) * S_;
    int p = invs[base + s];
    ushort4 v = *(const ushort4*)(outacc + (base + p) * C_ + cq * 4);
    sum.x += bf2f(v.x);
    sum.y += bf2f(v.y);
    sum.z += bf2f(v.z);
    sum.w += bf2f(v.w);
  }
  float4 rv = make_float4(sum.x * 0.25f, sum.y * 0.25f, sum.z * 0.25f, sum.w * 0.25f);
  *(float4*)(out + ((size_t)b * S_ + s) * C_ + cq * 4) = rv;
}

__global__ __launch_bounds__(256) void zero_kernel(float* __restrict__ out) {
  size_t i = (size_t)blockIdx.x * 256 + threadIdx.x;
  size_t n4 = (size_t)B_ * S_ * C_ / 4;
  if (i >= n4) return;
  *(float4*)(out + i * 4) = make_float4(0.f, 0.f, 0.f, 0.f);
}

extern "C" void kernel_launch(void* const* d_in, const int* in_sizes, int n_in,
                              void* d_out, int out_size, void* d_ws, size_t ws_size,
                              hipStream_t stream) {
  const float* in = (const float*)d_in[0];
  const float* RM = (const float*)d_in[1];
  float* out = (float*)d_out;
  const size_t r64_b  = (size_t)A_ * C_ * 64 * 8;        //   0.5 MB
  const size_t rpk_b  = (size_t)A_ * C_ * 64 * 2;        //   128 KB (each)
  const size_t key_b  = (size_t)B_ * A_ * SORTN * 8;     //   4.19 MB
  const size_t idx_b  = (size_t)B_ * A_ * S_ * 4;        //   1.18 MB
  const size_t inv_b  = (size_t)B_ * A_ * S_ * 4;        //   1.18 MB
  const size_t xf_b   = (size_t)B_ * S_ * C_ * 2;        //  37.7 MB (bf16)
  const size_t accw_b = (size_t)B_ * A_ * S_ * C_ * 2;   // 151 MB (bf16)
  char* ws = (char*)d_ws;
  size_t off = 0;
  double* R64 = (double*)(ws + off); off += r64_b;
  unsigned short* rpkhi = (unsigned short*)(ws + off); off += rpk_b;
  unsigned short* rpklo = (unsigned short*)(ws + off); off += rpk_b;
  unsigned long long* keys = (unsigned long long*)(ws + off); off += key_b;
  int* idxs = (int*)(ws + off); off += idx_b;
  int* invs = (int*)(ws + off); off += inv_b;
  int use_xf = ws_size >= off + xf_b;
  unsigned short* xf16 = nullptr;
  if (use_xf) { xf16 = (unsigned short*)(ws + off); off += xf_b; }
  int path_a = ws_size >= off + accw_b;
  unsigned short* outacc = nullptr;
  if (path_a) { outacc = (unsigned short*)(ws + off); off += accw_b; }

  cvt_r_kernel<<<dim3((A_ * C_ * 64 + 255) / 256), 256, 0, stream>>>(RM, R64, rpkhi, rpklo);
  if (use_xf)
    t_kernel<<<dim3(S_ / 32, C_ / 32, B_), 256, 0, stream>>>(in, xf16);
  hash_kernel<<<dim3(B_ * (S_ / 64)), 256, 0, stream>>>(in, R64, rpkhi, rpklo, keys);
  // ---- multi-block bitonic sort ----
  pad_kernel<<<dim3(B_ * A_ * (SORTN - S_) / 256), 256, 0, stream>>>(keys);
  sort_local_kernel<<<dim3(B_ * A_ * 8), 256, 0, stream>>>(keys);
  sort_merge_kernel<4096><<<dim3(B_ * A_ * 4), 512, 0, stream>>>(keys, 4096, 2048);
  sort_merge_kernel<8192><<<dim3(B_ * A_ * 2), 512, 0, stream>>>(keys, 8192, 4096);
  sort_gpass_kernel<<<dim3(B_ * A_ * 8192 / 256), 256, 0, stream>>>(keys);
  sort_final_kernel<<<dim3(B_ * A_ * 2), 512, 0, stream>>>(keys, idxs, invs);

  size_t n4 = (size_t)B_ * S_ * C_ / 4;
  int rb = (int)((n4 + 255) / 256);
  if (!path_a) zero_kernel<<<dim3(rb), 256, 0, stream>>>(out);
  attn_kernel<<<dim3(B_ * A_ * NB_), 512, 0, stream>>>(xf16, in, idxs, outacc, out, use_xf, path_a);
  if (path_a) reduce_kernel<<<dim3(rb), 256, 0, stream>>>(outacc, invs, out);
}